// Round 1
// baseline (1825.951 us; speedup 1.0000x reference)
//
#include <hip/hip_runtime.h>
#include <math.h>

#define NN 100000
#define NE 1000000
#define NR 1000
#define DD 100
#define OUTC 600
#define EPS 1e-12f

__device__ inline float wave_sum(float v) {
#pragma unroll
    for (int o = 32; o > 0; o >>= 1) v += __shfl_down(v, o, 64);
    return __shfl(v, 0, 64);
}

// row_ptr[n] = lower_bound(dst, n); dst is sorted ascending. row_ptr[NN] = NE.
__global__ void k_rowptr(const int* __restrict__ dst, int* __restrict__ row_ptr) {
    int n = blockIdx.x * blockDim.x + threadIdx.x;
    if (n > NN) return;
    int lo = 0, hi = NE;
    while (lo < hi) {
        int mid = (lo + hi) >> 1;
        if (dst[mid] < n) lo = mid + 1; else hi = mid;
    }
    row_ptr[n] = lo;
}

// rel_norm[r] = rel_emb[r] / max(||rel_emb[r]||, EPS) ; one wave per relation
__global__ void k_relnorm(const float* __restrict__ rel_emb, float* __restrict__ rel_norm) {
    int w = (blockIdx.x * blockDim.x + threadIdx.x) >> 6;
    int lane = threadIdx.x & 63;
    if (w >= NR) return;
    const float* r = rel_emb + w * DD;
    float v0 = r[lane];
    float v1 = (lane + 64 < DD) ? r[lane + 64] : 0.f;
    float ss = wave_sum(v0 * v0 + v1 * v1);
    float sc = 1.f / fmaxf(sqrtf(ss), EPS);
    float* o = rel_norm + w * DD;
    o[lane] = v0 * sc;
    if (lane + 64 < DD) o[lane + 64] = v1 * sc;
}

// segment means of ent_emb[src] and rel_emb[erel] over dst segments, tanh,
// write to out cols [0:100) (ent) and [300:400) (rel). One wave per node.
__global__ void k_segmean(const float* __restrict__ ent_emb, const float* __restrict__ rel_emb,
                          const int* __restrict__ src, const int* __restrict__ erel,
                          const int* __restrict__ row_ptr, float* __restrict__ out) {
    int w = (blockIdx.x * blockDim.x + threadIdx.x) >> 6;
    int lane = threadIdx.x & 63;
    if (w >= NN) return;
    int beg = row_ptr[w], end = row_ptr[w + 1];
    float aE0 = 0.f, aE1 = 0.f, aR0 = 0.f, aR1 = 0.f;
    for (int e = beg; e < end; ++e) {
        int s = src[e], r = erel[e];
        const float* es = ent_emb + (size_t)s * DD;
        const float* rr = rel_emb + (size_t)r * DD;
        aE0 += es[lane];
        aR0 += rr[lane];
        if (lane + 64 < DD) { aE1 += es[lane + 64]; aR1 += rr[lane + 64]; }
    }
    float inv = 1.f / fmaxf((float)(end - beg), 1.f);
    float* o = out + (size_t)w * OUTC;
    o[lane]       = tanhf(aE0 * inv);
    o[300 + lane] = tanhf(aR0 * inv);
    if (lane + 64 < DD) {
        o[64 + lane]  = tanhf(aE1 * inv);
        o[364 + lane] = tanhf(aR1 * inv);
    }
}

// per-node dots with w_s / w_n; feats live in out at column colF, row stride OUTC
__global__ void k_nodedot(const float* __restrict__ out, int colF,
                          const float* __restrict__ k3d,  // attn + l*300
                          float* __restrict__ sdot, float* __restrict__ ndot) {
    int w = (blockIdx.x * blockDim.x + threadIdx.x) >> 6;
    int lane = threadIdx.x & 63;
    if (w >= NN) return;
    const float* f = out + (size_t)w * OUTC + colF;
    float f0 = f[lane];
    float f1 = (lane + 64 < DD) ? f[lane + 64] : 0.f;
    float ws1 = 0.f, wn1 = 0.f;
    float ws0 = k3d[lane], wn0 = k3d[DD + lane];
    if (lane + 64 < DD) { ws1 = k3d[lane + 64]; wn1 = k3d[DD + lane + 64]; }
    float s  = wave_sum(f0 * ws0 + f1 * ws1);
    float nn = wave_sum(f0 * wn0 + f1 * wn1);
    if (lane == 0) { sdot[w] = s; ndot[w] = nn; }
}

// per-relation dots: rdot[r] = <rel_norm[r], w_r>, rwn[r] = <rel_norm[r], w_n>
__global__ void k_relv(const float* __restrict__ rel_norm, const float* __restrict__ k3d,
                       float* __restrict__ rdot, float* __restrict__ rwn) {
    int w = (blockIdx.x * blockDim.x + threadIdx.x) >> 6;
    int lane = threadIdx.x & 63;
    if (w >= NR) return;
    const float* r = rel_norm + w * DD;
    float r0 = r[lane];
    float r1 = (lane + 64 < DD) ? r[lane + 64] : 0.f;
    float wr1 = 0.f, wn1 = 0.f;
    float wr0 = k3d[2 * DD + lane], wn0 = k3d[DD + lane];
    if (lane + 64 < DD) { wr1 = k3d[2 * DD + lane + 64]; wn1 = k3d[DD + lane + 64]; }
    float rd = wave_sum(r0 * wr0 + r1 * wr1);
    float rn = wave_sum(r0 * wn0 + r1 * wn1);
    if (lane == 0) { rdot[w] = rd; rwn[w] = rn; }
}

// per-edge: dot_e = <feats[src], rel_norm[erel]>; logits. One wave per edge.
__global__ void k_edgelogits(const float* __restrict__ out, int colF,
                             const float* __restrict__ rel_norm,
                             const int* __restrict__ src, const int* __restrict__ dst,
                             const int* __restrict__ erel,
                             const float* __restrict__ sdot, const float* __restrict__ ndot,
                             const float* __restrict__ rdot, const float* __restrict__ rwn,
                             float* __restrict__ edot, float* __restrict__ elog) {
    int w = (blockIdx.x * blockDim.x + threadIdx.x) >> 6;
    int lane = threadIdx.x & 63;
    if (w >= NE) return;
    int s = src[w], d = dst[w], r = erel[w];
    const float* f = out + (size_t)s * OUTC + colF;
    const float* rn = rel_norm + r * DD;
    float p0 = f[lane] * rn[lane];
    float p1 = (lane + 64 < DD) ? f[lane + 64] * rn[lane + 64] : 0.f;
    float p = wave_sum(p0 + p1);
    if (lane == 0) {
        edot[w] = p;
        elog[w] = sdot[d] + ndot[s] - 2.f * p * rwn[r] + rdot[r];
    }
}

// segment softmax over dst segments, in-place logits -> attention. Thread per node.
__global__ void k_segsoftmax(const int* __restrict__ row_ptr, float* __restrict__ elog) {
    int n = blockIdx.x * blockDim.x + threadIdx.x;
    if (n >= NN) return;
    int beg = row_ptr[n], end = row_ptr[n + 1];
    if (beg >= end) return;
    float m = -INFINITY;
    for (int e = beg; e < end; ++e) m = fmaxf(m, elog[e]);
    float ssum = 0.f;
    for (int e = beg; e < end; ++e) ssum += expf(elog[e] - m);
    float inv = 1.f / ssum;
    for (int e = beg; e < end; ++e) elog[e] = expf(elog[e] - m) * inv;
}

// feats_new[n] = tanh( sum_e att_e * (feats[src_e] - 2*dot_e*rel_norm[erel_e]) )
// One wave per node. Reads colF block, writes colO block (disjoint).
__global__ void k_aggregate(const float* __restrict__ rel_norm,
                            const int* __restrict__ src, const int* __restrict__ erel,
                            const int* __restrict__ row_ptr,
                            const float* __restrict__ edot, const float* __restrict__ att,
                            float* __restrict__ out, int colF, int colO) {
    int w = (blockIdx.x * blockDim.x + threadIdx.x) >> 6;
    int lane = threadIdx.x & 63;
    if (w >= NN) return;
    int beg = row_ptr[w], end = row_ptr[w + 1];
    float a0 = 0.f, a1 = 0.f;
    for (int e = beg; e < end; ++e) {
        int s = src[e], r = erel[e];
        float at = att[e];
        float c = 2.f * edot[e];
        const float* f = out + (size_t)s * OUTC + colF;
        const float* rn = rel_norm + r * DD;
        a0 += at * (f[lane] - c * rn[lane]);
        if (lane + 64 < DD) a1 += at * (f[lane + 64] - c * rn[lane + 64]);
    }
    float* o = out + (size_t)w * OUTC + colO;
    o[lane] = tanhf(a0);
    if (lane + 64 < DD) o[lane + 64] = tanhf(a1);
}

extern "C" void kernel_launch(void* const* d_in, const int* in_sizes, int n_in,
                              void* d_out, int out_size, void* d_ws, size_t ws_size,
                              hipStream_t stream) {
    const float* ent_emb = (const float*)d_in[0];
    const float* rel_emb = (const float*)d_in[1];
    const float* attn_e  = (const float*)d_in[2];
    const float* attn_r  = (const float*)d_in[3];
    const int*   src     = (const int*)d_in[4];
    const int*   dst     = (const int*)d_in[5];
    const int*   erel    = (const int*)d_in[6];
    float* out = (float*)d_out;

    char* ws = (char*)d_ws;
    size_t off = 0;
    auto alloc = [&](size_t bytes) -> void* {
        void* p = ws + off;
        off = (off + bytes + 255) & ~(size_t)255;
        return p;
    };
    int*   row_ptr  = (int*)alloc((NN + 1) * sizeof(int));
    float* rel_norm = (float*)alloc((size_t)NR * DD * sizeof(float));
    float* sdot     = (float*)alloc(NN * sizeof(float));
    float* ndot     = (float*)alloc(NN * sizeof(float));
    float* rdot     = (float*)alloc(NR * sizeof(float));
    float* rwn      = (float*)alloc(NR * sizeof(float));
    float* edot     = (float*)alloc((size_t)NE * sizeof(float));
    float* elog     = (float*)alloc((size_t)NE * sizeof(float));

    hipLaunchKernelGGL(k_rowptr, dim3((NN + 256) / 256), dim3(256), 0, stream, dst, row_ptr);
    hipLaunchKernelGGL(k_relnorm, dim3((NR * 64 + 255) / 256), dim3(256), 0, stream, rel_emb, rel_norm);
    hipLaunchKernelGGL(k_segmean, dim3(NN / 4), dim3(256), 0, stream,
                       ent_emb, rel_emb, src, erel, row_ptr, out);

    for (int enc = 0; enc < 2; ++enc) {
        const float* attn = (enc == 0) ? attn_e : attn_r;
        int colbase = enc * 300;
        for (int l = 0; l < 2; ++l) {
            int colF = colbase + l * 100;
            int colO = colF + 100;
            const float* k3d = attn + l * 300;
            hipLaunchKernelGGL(k_nodedot, dim3(NN / 4), dim3(256), 0, stream, out, colF, k3d, sdot, ndot);
            hipLaunchKernelGGL(k_relv, dim3((NR * 64 + 255) / 256), dim3(256), 0, stream, rel_norm, k3d, rdot, rwn);
            hipLaunchKernelGGL(k_edgelogits, dim3(NE / 4), dim3(256), 0, stream,
                               out, colF, rel_norm, src, dst, erel, sdot, ndot, rdot, rwn, edot, elog);
            hipLaunchKernelGGL(k_segsoftmax, dim3((NN + 255) / 256), dim3(256), 0, stream, row_ptr, elog);
            hipLaunchKernelGGL(k_aggregate, dim3(NN / 4), dim3(256), 0, stream,
                               rel_norm, src, erel, row_ptr, edot, elog, out, colF, colO);
        }
    }
}

// Round 2
// 1439.216 us; speedup vs baseline: 1.2687x; 1.2687x over previous
//
#include <hip/hip_runtime.h>
#include <math.h>

#define NN 100000
#define NE 1000000
#define NR 1000
#define DD 100
#define OUTC 600
#define EPS 1e-12f
#define CHUNK 16

__device__ inline float wave_sum(float v) {
#pragma unroll
    for (int o = 32; o > 0; o >>= 1) v += __shfl_down(v, o, 64);
    return __shfl(v, 0, 64);
}
// max over lanes 0..15 (lanes 16..63 must hold -inf); broadcast to all lanes
__device__ inline float grp16_max_bcast(float v) {
#pragma unroll
    for (int o = 8; o > 0; o >>= 1) v = fmaxf(v, __shfl_xor(v, o, 64));
    return __shfl(v, 0, 64);
}
// sum over lanes 0..15 (lanes 16..63 must hold 0); broadcast to all lanes
__device__ inline float grp16_sum_bcast(float v) {
#pragma unroll
    for (int o = 8; o > 0; o >>= 1) v += __shfl_xor(v, o, 64);
    return __shfl(v, 0, 64);
}

// row_ptr[n] = lower_bound(dst, n); dst sorted ascending. row_ptr[NN] = NE.
__global__ void k_rowptr(const int* __restrict__ dst, int* __restrict__ row_ptr) {
    int n = blockIdx.x * blockDim.x + threadIdx.x;
    if (n > NN) return;
    int lo = 0, hi = NE;
    while (lo < hi) {
        int mid = (lo + hi) >> 1;
        if (dst[mid] < n) lo = mid + 1; else hi = mid;
    }
    row_ptr[n] = lo;
}

// rel_norm[r] = rel_emb[r] / max(||rel_emb[r]||, EPS); one wave per relation
__global__ void k_relnorm(const float* __restrict__ rel_emb, float* __restrict__ rel_norm) {
    int w = (blockIdx.x * blockDim.x + threadIdx.x) >> 6;
    int lane = threadIdx.x & 63;
    if (w >= NR) return;
    const float* r = rel_emb + w * DD;
    float v0 = r[lane];
    float v1 = (lane + 64 < DD) ? r[lane + 64] : 0.f;
    float ss = wave_sum(v0 * v0 + v1 * v1);
    float sc = 1.f / fmaxf(sqrtf(ss), EPS);
    float* o = rel_norm + w * DD;
    o[lane] = v0 * sc;
    if (lane + 64 < DD) o[lane + 64] = v1 * sc;
}

// tanh(segment-mean of table[idx[e]]) over dst segments. One wave per node.
// Writes F (stride fstride); optionally duplicates to outcol (stride OUTC).
__global__ void k_segmean(const float* __restrict__ table, const int* __restrict__ idx,
                          const int* __restrict__ row_ptr,
                          float* __restrict__ F, long long fstride,
                          float* __restrict__ outcol, int dup) {
    int w = (blockIdx.x * blockDim.x + threadIdx.x) >> 6;
    int lane = threadIdx.x & 63;
    if (w >= NN) return;
    int beg = row_ptr[w], end = row_ptr[w + 1];
    float a0 = 0.f, a1 = 0.f;
    for (int e = beg; e < end; ++e) {
        int t = idx[e];
        const float* row = table + (size_t)t * DD;
        a0 += row[lane];
        if (lane + 64 < DD) a1 += row[lane + 64];
    }
    float inv = 1.f / fmaxf((float)(end - beg), 1.f);
    float o0 = tanhf(a0 * inv);
    float o1 = tanhf(a1 * inv);
    float* f = F + (size_t)w * fstride;
    f[lane] = o0;
    if (lane + 64 < DD) f[lane + 64] = o1;
    if (dup) {
        float* o = outcol + (size_t)w * OUTC;
        o[lane] = o0;
        if (lane + 64 < DD) o[lane + 64] = o1;
    }
}

// per-node dots with w_s / w_n from feats F (stride fstride)
__global__ void k_nodedot(const float* __restrict__ F, long long fstride,
                          const float* __restrict__ k3d,
                          float* __restrict__ sdot, float* __restrict__ ndot) {
    int w = (blockIdx.x * blockDim.x + threadIdx.x) >> 6;
    int lane = threadIdx.x & 63;
    if (w >= NN) return;
    const float* f = F + (size_t)w * fstride;
    float f0 = f[lane];
    float f1 = (lane + 64 < DD) ? f[lane + 64] : 0.f;
    float ws1 = 0.f, wn1 = 0.f;
    float ws0 = k3d[lane], wn0 = k3d[DD + lane];
    if (lane + 64 < DD) { ws1 = k3d[lane + 64]; wn1 = k3d[DD + lane + 64]; }
    float s  = wave_sum(f0 * ws0 + f1 * ws1);
    float nn = wave_sum(f0 * wn0 + f1 * wn1);
    if (lane == 0) { sdot[w] = s; ndot[w] = nn; }
}

// per-relation dots: rdot[r] = <rel_norm[r], w_r>, rwn[r] = <rel_norm[r], w_n>
__global__ void k_relv(const float* __restrict__ rel_norm, const float* __restrict__ k3d,
                       float* __restrict__ rdot, float* __restrict__ rwn) {
    int w = (blockIdx.x * blockDim.x + threadIdx.x) >> 6;
    int lane = threadIdx.x & 63;
    if (w >= NR) return;
    const float* r = rel_norm + w * DD;
    float r0 = r[lane];
    float r1 = (lane + 64 < DD) ? r[lane + 64] : 0.f;
    float wr1 = 0.f, wn1 = 0.f;
    float wr0 = k3d[2 * DD + lane], wn0 = k3d[DD + lane];
    if (lane + 64 < DD) { wr1 = k3d[2 * DD + lane + 64]; wn1 = k3d[DD + lane + 64]; }
    float rd = wave_sum(r0 * wr0 + r1 * wr1);
    float rn = wave_sum(r0 * wn0 + r1 * wn1);
    if (lane == 0) { rdot[w] = rd; rwn[w] = rn; }
}

// Fused layer: logits + segment softmax (online, 16-edge chunks) + aggregate.
// One wave per node. Each edge's feats row is gathered ONCE; the reflected
// neighbor row is parked in LDS for the weighted-accumulate pass.
__global__ __launch_bounds__(256) void k_layer(
        const float* __restrict__ F, long long fstride,
        const float* __restrict__ rel_norm,
        const int* __restrict__ src, const int* __restrict__ erel,
        const int* __restrict__ row_ptr,
        const float* __restrict__ sdot, const float* __restrict__ ndot,
        const float* __restrict__ rdot, const float* __restrict__ rwn,
        float* __restrict__ Fnext, long long fnstride,
        float* __restrict__ outcol, int dup) {
    __shared__ float s_nei[4][CHUNK][DD];
    int wid = threadIdx.x >> 6;
    int lane = threadIdx.x & 63;
    int n = blockIdx.x * 4 + wid;
    if (n >= NN) return;
    int beg = row_ptr[n], end = row_ptr[n + 1];
    float sd = sdot[n];
    float acc0 = 0.f, acc1 = 0.f;
    float m_run = -INFINITY, l_run = 0.f;
    for (int cb = beg; cb < end; cb += CHUNK) {
        int cnt = min(CHUNK, end - cb);
        // coalesced preload of per-edge scalars into lanes 0..cnt-1
        int s_l = 0, r_l = 0;
        float nd_l = 0.f, rd_l = 0.f, rw_l = 0.f;
        if (lane < cnt) {
            s_l = src[cb + lane];
            r_l = erel[cb + lane];
            nd_l = ndot[s_l];
            rd_l = rdot[r_l];
            rw_l = rwn[r_l];
        }
        float lg_l = -INFINITY;
        for (int j = 0; j < cnt; ++j) {
            int s = __shfl(s_l, j, 64);
            int r = __shfl(r_l, j, 64);
            const float* f = F + (size_t)s * fstride;
            const float* rn = rel_norm + r * DD;
            float f0 = f[lane], r0 = rn[lane];
            float f1 = 0.f, r1 = 0.f;
            if (lane + 64 < DD) { f1 = f[lane + 64]; r1 = rn[lane + 64]; }
            float p = wave_sum(f0 * r0 + f1 * r1);
            float c = 2.f * p;
            s_nei[wid][j][lane] = f0 - c * r0;
            if (lane + 64 < DD) s_nei[wid][j][lane + 64] = f1 - c * r1;
            float lg = sd + __shfl(nd_l, j, 64) - c * __shfl(rw_l, j, 64)
                       + __shfl(rd_l, j, 64);
            if (lane == j) lg_l = lg;
        }
        // online softmax update over this chunk
        float mc = grp16_max_bcast(lg_l);
        float m_new = fmaxf(m_run, mc);
        float scale = __expf(m_run - m_new);   // exp(-inf)=0 on first chunk
        acc0 *= scale; acc1 *= scale; l_run *= scale;
        float w_l = (lane < cnt) ? __expf(lg_l - m_new) : 0.f;
        l_run += grp16_sum_bcast(w_l);
        m_run = m_new;
        for (int j = 0; j < cnt; ++j) {
            float w = __shfl(w_l, j, 64);
            acc0 += w * s_nei[wid][j][lane];
            if (lane + 64 < DD) acc1 += w * s_nei[wid][j][lane + 64];
        }
    }
    float o0 = 0.f, o1 = 0.f;
    if (end > beg) {
        float inv = 1.f / l_run;
        o0 = tanhf(acc0 * inv);
        o1 = tanhf(acc1 * inv);
    }
    float* fo = Fnext + (size_t)n * fnstride;
    fo[lane] = o0;
    if (lane + 64 < DD) fo[lane + 64] = o1;
    if (dup) {
        float* oc = outcol + (size_t)n * OUTC;
        oc[lane] = o0;
        if (lane + 64 < DD) oc[lane + 64] = o1;
    }
}

extern "C" void kernel_launch(void* const* d_in, const int* in_sizes, int n_in,
                              void* d_out, int out_size, void* d_ws, size_t ws_size,
                              hipStream_t stream) {
    const float* ent_emb = (const float*)d_in[0];
    const float* rel_emb = (const float*)d_in[1];
    const float* attn_e  = (const float*)d_in[2];
    const float* attn_r  = (const float*)d_in[3];
    const int*   src     = (const int*)d_in[4];
    const int*   dst     = (const int*)d_in[5];
    const int*   erel    = (const int*)d_in[6];
    float* out = (float*)d_out;

    char* ws = (char*)d_ws;
    size_t off = 0;
    auto alloc = [&](size_t bytes) -> void* {
        void* p = ws + off;
        off = (off + bytes + 255) & ~(size_t)255;
        return p;
    };
    int*   row_ptr  = (int*)alloc((NN + 1) * sizeof(int));
    float* rel_norm = (float*)alloc((size_t)NR * DD * sizeof(float));
    float* sdot     = (float*)alloc(NN * sizeof(float));
    float* ndot     = (float*)alloc(NN * sizeof(float));
    float* rdot     = (float*)alloc(NR * sizeof(float));
    float* rwn      = (float*)alloc(NR * sizeof(float));
    size_t small_end = off;
    float* featsA   = (float*)alloc((size_t)NN * DD * sizeof(float));
    float* featsB   = (float*)alloc((size_t)NN * DD * sizeof(float));
    bool compact = (off <= ws_size);
    (void)small_end;

    hipLaunchKernelGGL(k_rowptr, dim3((NN + 256) / 256), dim3(256), 0, stream, dst, row_ptr);
    hipLaunchKernelGGL(k_relnorm, dim3(NR * 64 / 256), dim3(256), 0, stream, rel_emb, rel_norm);

    for (int enc = 0; enc < 2; ++enc) {
        const float* attn = (enc == 0) ? attn_e : attn_r;
        const float* table = (enc == 0) ? ent_emb : rel_emb;
        const int*   idx   = (enc == 0) ? src : erel;
        int colbase = enc * 300;

        float* F;   long long fs;
        float* Fn;  long long fns;
        if (compact) {
            F = featsA; fs = DD; Fn = featsB; fns = DD;
            hipLaunchKernelGGL(k_segmean, dim3(NN / 4), dim3(256), 0, stream,
                               table, idx, row_ptr, F, fs, out + colbase, 1);
        } else {
            F = out + colbase; fs = OUTC;
            hipLaunchKernelGGL(k_segmean, dim3(NN / 4), dim3(256), 0, stream,
                               table, idx, row_ptr, F, fs, (float*)nullptr, 0);
        }

        for (int l = 0; l < 2; ++l) {
            int colO = colbase + (l + 1) * 100;
            const float* k3d = attn + l * 300;
            hipLaunchKernelGGL(k_nodedot, dim3(NN / 4), dim3(256), 0, stream,
                               F, fs, k3d, sdot, ndot);
            hipLaunchKernelGGL(k_relv, dim3(NR * 64 / 256), dim3(256), 0, stream,
                               rel_norm, k3d, rdot, rwn);
            if (compact) {
                float* Fnx = (l == 0) ? featsB : featsA;  // ping-pong
                hipLaunchKernelGGL(k_layer, dim3(NN / 4), dim3(256), 0, stream,
                                   F, fs, rel_norm, src, erel, row_ptr,
                                   sdot, ndot, rdot, rwn,
                                   Fnx, (long long)DD, out + colO, 1);
                F = Fnx; fs = DD;
            } else {
                hipLaunchKernelGGL(k_layer, dim3(NN / 4), dim3(256), 0, stream,
                                   F, fs, rel_norm, src, erel, row_ptr,
                                   sdot, ndot, rdot, rwn,
                                   out + colO, (long long)OUTC, (float*)nullptr, 0);
                F = out + colO; fs = OUTC;
            }
        }
    }
}